// Round 15
// baseline (135.969 us; speedup 1.0000x reference)
//
#include <hip/hip_runtime.h>
#include <stdint.h>

#define QCNT 256
#define NKEYS 10000
#define DDIM 128
#define KSEL 10
#define OBSROW 28224  // 4*84*84

typedef float f4v __attribute__((ext_vector_type(4)));
typedef float f32x4 __attribute__((ext_vector_type(4)));
typedef _Float16 f16x8 __attribute__((ext_vector_type(8)));

// ---------------- MFMA path geometry (R12-proven) ----------------
#define QTILE 16                              // queries per block (MFMA N)
#define KCHUNK 48                             // keys per chunk (3 MFMA tiles)
#define NTILES 3
#define NCHUNK_M ((NKEYS + KCHUNK - 1) / KCHUNK)  // 209 (last: 16 valid keys)
#define LISTM 10

// Monotone (dist, idx) -> u64; dist may be negative (q2 dropped).
__device__ inline unsigned long long enc_key(float d, int n) {
  unsigned u = __float_as_uint(d);
  u ^= (unsigned)((int)u >> 31) | 0x80000000u;
  return ((unsigned long long)u << 32) | (unsigned)n;
}

__device__ inline unsigned long long wave_min_u64(unsigned long long w) {
#pragma unroll
  for (int off = 1; off < 64; off <<= 1) {
    unsigned long long o =
        (unsigned long long)__shfl_xor((long long)w, off, 64);
    if (o < w) w = o;
  }
  return w;
}

__device__ inline void insert10(unsigned long long best[LISTM],
                                unsigned long long key) {
  if (key < best[LISTM - 1]) {
    best[LISTM - 1] = key;
#pragma unroll
    for (int s = LISTM - 1; s >= 1; --s) {
      if (best[s] < best[s - 1]) {
        unsigned long long t = best[s];
        best[s] = best[s - 1];
        best[s - 1] = t;
      }
    }
  }
}

// ---------------------------------------------------------------------------
// Kernel 1: fused prep + MFMA part — EXACT R12 configuration.
// R15: launched TWICE (idempotent, deterministic) purely to measure its
// duration as (dur_R15 - 117.3). Remove the duplicate next round.
// ---------------------------------------------------------------------------
__global__ __launch_bounds__(64) void knn_part_fused(
    const float* __restrict__ q, const float* __restrict__ k,
    unsigned long long* __restrict__ part) {
  const int qt   = blockIdx.x;   // 0..15
  const int ch   = blockIdx.y;   // 0..208
  const int lane = threadIdx.x;  // 0..63
  const int lq   = lane & 15;
  const int lk8  = (lane >> 4) * 8;
  const int q0   = qt * QTILE;

  // B fragments (queries) once per block: load fp32, convert hi/lo in-reg.
  f16x8 bh[4], bl[4];
  {
    const float* qrow = q + (size_t)(q0 + lq) * DDIM + lk8;
#pragma unroll
    for (int kc = 0; kc < 4; ++kc) {
      f4v v0 = *(const f4v*)(qrow + kc * 32);
      f4v v1 = *(const f4v*)(qrow + kc * 32 + 4);
      float e[8] = {v0.x, v0.y, v0.z, v0.w, v1.x, v1.y, v1.z, v1.w};
#pragma unroll
      for (int j = 0; j < 8; ++j) {
        _Float16 h = (_Float16)e[j];
        bh[kc][j]  = h;
        bl[kc][j]  = (_Float16)(e[j] - (float)h);
      }
    }
  }

  unsigned long long list[LISTM];
#pragma unroll
  for (int s = 0; s < LISTM; ++s) list[s] = ~0ULL;

  const int kbase = ch * KCHUNK;
#pragma unroll
  for (int t = 0; t < NTILES; ++t) {
    const int tb = kbase + t * 16;
    int row      = tb + lq;
    if (row > NKEYS - 1) row = NKEYS - 1;  // clamp (tail chunk only)
    const float* arow = k + (size_t)row * DDIM + lk8;

    f32x4 acc = {0.f, 0.f, 0.f, 0.f};
    float k2p = 0.f;
#pragma unroll
    for (int kc = 0; kc < 4; ++kc) {
      f4v a0 = *(const f4v*)(arow + kc * 32);
      f4v a1 = *(const f4v*)(arow + kc * 32 + 4);
      float e[8] = {a0.x, a0.y, a0.z, a0.w, a1.x, a1.y, a1.z, a1.w};
      f16x8 ah, al;
#pragma unroll
      for (int j = 0; j < 8; ++j) {
        _Float16 h = (_Float16)e[j];
        ah[j]      = h;
        al[j]      = (_Float16)(e[j] - (float)h);
        k2p        = fmaf(e[j], e[j], k2p);  // exact fp32 from fp32 data
      }
      acc = __builtin_amdgcn_mfma_f32_16x16x32_f16(ah, bh[kc], acc, 0, 0, 0);
      acc = __builtin_amdgcn_mfma_f32_16x16x32_f16(ah, bl[kc], acc, 0, 0, 0);
      acc = __builtin_amdgcn_mfma_f32_16x16x32_f16(al, bh[kc], acc, 0, 0, 0);
    }

    // Full ||row||^2: 4-lane tree over the lq-sharing group, then
    // redistribute to the D-layout rows (lane>>4)*4 + reg.
    k2p += __shfl_xor(k2p, 16, 64);
    k2p += __shfl_xor(k2p, 32, 64);
    const int rb = (lane >> 4) * 4;
    const int r0 = tb + rb;
#pragma unroll
    for (int reg = 0; reg < 4; ++reg) {
      float k2v = __shfl(k2p, rb + reg, 64);
      const int n = r0 + reg;
      if (n < NKEYS) {
        insert10(list, enc_key(fmaf(-2.f, acc[reg], k2v), n));
      }
    }
  }

  // Tombstone-extract top-10 across the 4 lanes sharing query lq.
  unsigned long long* dst =
      part + ((size_t)(q0 + lq) * NCHUNK_M + ch) * KSEL;
#pragma unroll 1
  for (int r = 0; r < KSEL; ++r) {
    unsigned long long w = list[0];
    {
      unsigned long long o =
          (unsigned long long)__shfl_xor((long long)w, 16, 64);
      if (o < w) w = o;
      o = (unsigned long long)__shfl_xor((long long)w, 32, 64);
      if (o < w) w = o;
    }
    if (list[0] == w) {
#pragma unroll
      for (int s = 0; s < LISTM - 1; ++s) list[s] = list[s + 1];
      list[LISTM - 1] = ~0ULL;
    }
    if (lane < 16) dst[r] = w;
  }
}

// ---------------------------------------------------------------------------
// Kernel 2: fused merge + gather — EXACT R12 configuration: wave 0 merges
// the query's 2090 candidates, one __syncthreads, LDS-broadcast src, then
// the proven copy (cached loads + NT stores).
// ---------------------------------------------------------------------------
template <int NCHUNK_T>
__global__ __launch_bounds__(256) void knn_merge_gather_kernel(
    const float* __restrict__ obs, const unsigned long long* __restrict__ part,
    float* __restrict__ out) {
  constexpr int NCAND_T = NCHUNK_T * KSEL;
  constexpr int SLOTS   = (NCAND_T + 63) / 64;

  const int b    = blockIdx.x;  // b = r*QCNT + q
  const int r    = b >> 8;
  const int qq   = b & 255;
  const int tid  = threadIdx.x;

  __shared__ int s_src;

  if (tid < 64) {
    const unsigned long long* cp = part + (size_t)qq * NCAND_T;
    unsigned long long c[SLOTS];
#pragma unroll
    for (int i = 0; i < SLOTS; ++i) {
      const int idx = tid + 64 * i;
      c[i] = (idx < NCAND_T) ? cp[idx] : ~0ULL;
    }
    unsigned long long w = ~0ULL;
#pragma unroll 1
    for (int round = 0; round <= r; ++round) {
      unsigned long long m = c[0];
#pragma unroll
      for (int i = 1; i < SLOTS; ++i) m = (c[i] < m) ? c[i] : m;
      w = wave_min_u64(m);
#pragma unroll
      for (int i = 0; i < SLOTS; ++i)
        if (c[i] == w) c[i] = ~0ULL;
    }
    if (tid == 0) s_src = (int)(w & 0xffffffffu);
  }
  __syncthreads();
  const int src = __builtin_amdgcn_readfirstlane(s_src);

  const f4v* __restrict__ s = (const f4v*)(obs + (size_t)src * OBSROW);
  f4v* __restrict__ d       = (f4v*)(out + (size_t)b * OBSROW);
#pragma unroll 4
  for (int i = tid; i < OBSROW / 4; i += 256) {
    f4v v = s[i];  // cached load: L3 catches duplicate rows
    __builtin_nontemporal_store(v, &d[i]);
  }
}

extern "C" void kernel_launch(void* const* d_in, const int* in_sizes, int n_in,
                              void* d_out, int out_size, void* d_ws,
                              size_t ws_size, hipStream_t stream) {
  const float* q   = (const float*)d_in[0];  // [256,128]
  const float* k   = (const float*)d_in[1];  // [10000,128]
  const float* obs = (const float*)d_in[2];  // [10000,4,84,84]
  float* out = (float*)d_out;                // [10,256,4,84,84]

  // ws: part buffer = 256 * 209 * 10 * 8 = 4,279,040 B.
  unsigned long long* part = (unsigned long long*)d_ws;

  // MEASUREMENT: part launched twice (idempotent, deterministic).
  // dur(R15) - 117.3 = part's true duration. Remove duplicate next round.
  knn_part_fused<<<dim3(QCNT / QTILE, NCHUNK_M), 64, 0, stream>>>(q, k, part);
  knn_part_fused<<<dim3(QCNT / QTILE, NCHUNK_M), 64, 0, stream>>>(q, k, part);
  knn_merge_gather_kernel<NCHUNK_M>
      <<<KSEL * QCNT, 256, 0, stream>>>(obs, part, out);
}

// Round 16
// 111.901 us; speedup vs baseline: 1.2151x; 1.2151x over previous
//
#include <hip/hip_runtime.h>
#include <stdint.h>

#define QCNT 256
#define NKEYS 10000
#define DDIM 128
#define KSEL 10
#define OBSROW 28224  // 4*84*84

typedef float f4v __attribute__((ext_vector_type(4)));
typedef float f32x4 __attribute__((ext_vector_type(4)));
typedef _Float16 f16x8 __attribute__((ext_vector_type(8)));

// ---------------- MFMA path geometry ----------------
#define QTILE 64                              // queries per block (4 waves)
#define KCHUNK 48                             // keys per chunk (3 MFMA tiles)
#define NTILES 3
#define NCHUNK_M ((NKEYS + KCHUNK - 1) / KCHUNK)  // 209 (last: 16 valid keys)
#define LISTM 10
#define RSTRH 136  // LDS row stride in halves (128 + 8 pad) = 272 B, 16B-align

// Monotone (dist, idx) -> u64; dist may be negative (q2 dropped).
__device__ inline unsigned long long enc_key(float d, int n) {
  unsigned u = __float_as_uint(d);
  u ^= (unsigned)((int)u >> 31) | 0x80000000u;
  return ((unsigned long long)u << 32) | (unsigned)n;
}

__device__ inline unsigned long long wave_min_u64(unsigned long long w) {
#pragma unroll
  for (int off = 1; off < 64; off <<= 1) {
    unsigned long long o =
        (unsigned long long)__shfl_xor((long long)w, off, 64);
    if (o < w) w = o;
  }
  return w;
}

__device__ inline void insert10(unsigned long long best[LISTM],
                                unsigned long long key) {
  if (key < best[LISTM - 1]) {
    best[LISTM - 1] = key;
#pragma unroll
    for (int s = LISTM - 1; s >= 1; --s) {
      if (best[s] < best[s - 1]) {
        unsigned long long t = best[s];
        best[s] = best[s - 1];
        best[s - 1] = t;
      }
    }
  }
}

// ---------------------------------------------------------------------------
// Kernel 1 (R16): LDS-shared k staging. Block = 256 threads = 4 waves;
// wave w handles queries qt*64 + w*16 .. +15 against the SAME 48-key chunk.
// Staging (once per block, one barrier): 48 k-rows loaded fp32, converted
// to split-fp16 hi/lo + per-row exact fp32 k2, written to LDS. All 4 waves
// then consume the LDS copy -> k L2/L3 traffic cut 4x vs R12 (82 -> 20.5
// MB), conversion VALU done once instead of per wave, per-tile k2 shfl tree
// replaced by one LDS broadcast read. MFMA math identical to R12 (split-
// fp16 3-MFMA, m89 D-layout). Tail chunk: clamped loads, guarded inserts.
// ---------------------------------------------------------------------------
__global__ __launch_bounds__(256) void knn_part_fused(
    const float* __restrict__ q, const float* __restrict__ k,
    unsigned long long* __restrict__ part) {
  const int qt  = blockIdx.x;  // 0..3
  const int ch  = blockIdx.y;  // 0..208
  const int tid = threadIdx.x;

  __shared__ _Float16 khi_l[KCHUNK * RSTRH];  // 13056 B
  __shared__ _Float16 klo_l[KCHUNK * RSTRH];  // 13056 B
  __shared__ float k2_l[KCHUNK];              // 192 B

  const int kbase = ch * KCHUNK;

  // ---- Stage: thread handles row (tile*16 + tid>>4), cols (tid&15)*8..+7.
#pragma unroll
  for (int t = 0; t < NTILES; ++t) {
    const int row  = t * 16 + (tid >> 4);  // 0..47
    const int col8 = tid & 15;             // 8-float column group
    int gr = kbase + row;
    if (gr > NKEYS - 1) gr = NKEYS - 1;  // clamp (tail chunk only)
    const float* src = k + (size_t)gr * DDIM + col8 * 8;
    f4v a0 = *(const f4v*)(src);
    f4v a1 = *(const f4v*)(src + 4);
    float e[8] = {a0.x, a0.y, a0.z, a0.w, a1.x, a1.y, a1.z, a1.w};
    f16x8 hv, lv;
    float k2p = 0.f;
#pragma unroll
    for (int j = 0; j < 8; ++j) {
      _Float16 h = (_Float16)e[j];
      hv[j]      = h;
      lv[j]      = (_Float16)(e[j] - (float)h);
      k2p        = fmaf(e[j], e[j], k2p);  // exact fp32
    }
    *(f16x8*)(khi_l + row * RSTRH + col8 * 8) = hv;
    *(f16x8*)(klo_l + row * RSTRH + col8 * 8) = lv;
    // Row sum: 16 consecutive lanes share a row (same wave).
    k2p += __shfl_xor(k2p, 1, 16);
    k2p += __shfl_xor(k2p, 2, 16);
    k2p += __shfl_xor(k2p, 4, 16);
    k2p += __shfl_xor(k2p, 8, 16);
    if ((tid & 15) == 0) k2_l[row] = k2p;
  }
  __syncthreads();  // the only barrier

  // ---- Compute: per wave, 16 queries vs the 48 staged keys.
  const int wv   = tid >> 6;
  const int lane = tid & 63;
  const int lq   = lane & 15;
  const int lk8  = (lane >> 4) * 8;  // k-offset within 32-elem kc block
  const int q0   = qt * QTILE + wv * 16;

  // B fragments (queries) per wave: load fp32, convert hi/lo in-reg.
  f16x8 bh[4], bl[4];
  {
    const float* qrow = q + (size_t)(q0 + lq) * DDIM + lk8;
#pragma unroll
    for (int kc = 0; kc < 4; ++kc) {
      f4v v0 = *(const f4v*)(qrow + kc * 32);
      f4v v1 = *(const f4v*)(qrow + kc * 32 + 4);
      float e[8] = {v0.x, v0.y, v0.z, v0.w, v1.x, v1.y, v1.z, v1.w};
#pragma unroll
      for (int j = 0; j < 8; ++j) {
        _Float16 h = (_Float16)e[j];
        bh[kc][j]  = h;
        bl[kc][j]  = (_Float16)(e[j] - (float)h);
      }
    }
  }

  unsigned long long list[LISTM];
#pragma unroll
  for (int s = 0; s < LISTM; ++s) list[s] = ~0ULL;

#pragma unroll
  for (int t = 0; t < NTILES; ++t) {
    const int rowb = t * 16;
    const _Float16* ah_p = khi_l + (rowb + lq) * RSTRH + lk8;
    const _Float16* al_p = klo_l + (rowb + lq) * RSTRH + lk8;

    f32x4 acc = {0.f, 0.f, 0.f, 0.f};
#pragma unroll
    for (int kc = 0; kc < 4; ++kc) {
      f16x8 ah = *(const f16x8*)(ah_p + kc * 32);
      f16x8 al = *(const f16x8*)(al_p + kc * 32);
      acc = __builtin_amdgcn_mfma_f32_16x16x32_f16(ah, bh[kc], acc, 0, 0, 0);
      acc = __builtin_amdgcn_mfma_f32_16x16x32_f16(ah, bl[kc], acc, 0, 0, 0);
      acc = __builtin_amdgcn_mfma_f32_16x16x32_f16(al, bh[kc], acc, 0, 0, 0);
    }

    const int rb = (lane >> 4) * 4;          // D-layout row base within tile
    f32x4 k2v = *(const f32x4*)(k2_l + rowb + rb);  // broadcast read
    const int r0 = kbase + rowb + rb;
#pragma unroll
    for (int reg = 0; reg < 4; ++reg) {
      const int n = r0 + reg;
      if (n < NKEYS) {
        insert10(list, enc_key(fmaf(-2.f, acc[reg], k2v[reg]), n));
      }
    }
  }

  // Tombstone-extract top-10 across the 4 lanes sharing query lq.
  unsigned long long* dst =
      part + ((size_t)(q0 + lq) * NCHUNK_M + ch) * KSEL;
#pragma unroll 1
  for (int r = 0; r < KSEL; ++r) {
    unsigned long long w = list[0];
    {
      unsigned long long o =
          (unsigned long long)__shfl_xor((long long)w, 16, 64);
      if (o < w) w = o;
      o = (unsigned long long)__shfl_xor((long long)w, 32, 64);
      if (o < w) w = o;
    }
    if (list[0] == w) {
#pragma unroll
      for (int s = 0; s < LISTM - 1; ++s) list[s] = list[s + 1];
      list[LISTM - 1] = ~0ULL;
    }
    if (lane < 16) dst[r] = w;
  }
}

// ---------------------------------------------------------------------------
// Kernel 2: fused merge + gather — EXACT R12 configuration: wave 0 merges
// the query's 2090 candidates, one __syncthreads, LDS-broadcast src, then
// the proven copy (cached loads + NT stores).
// ---------------------------------------------------------------------------
template <int NCHUNK_T>
__global__ __launch_bounds__(256) void knn_merge_gather_kernel(
    const float* __restrict__ obs, const unsigned long long* __restrict__ part,
    float* __restrict__ out) {
  constexpr int NCAND_T = NCHUNK_T * KSEL;
  constexpr int SLOTS   = (NCAND_T + 63) / 64;

  const int b    = blockIdx.x;  // b = r*QCNT + q
  const int r    = b >> 8;
  const int qq   = b & 255;
  const int tid  = threadIdx.x;

  __shared__ int s_src;

  if (tid < 64) {
    const unsigned long long* cp = part + (size_t)qq * NCAND_T;
    unsigned long long c[SLOTS];
#pragma unroll
    for (int i = 0; i < SLOTS; ++i) {
      const int idx = tid + 64 * i;
      c[i] = (idx < NCAND_T) ? cp[idx] : ~0ULL;
    }
    unsigned long long w = ~0ULL;
#pragma unroll 1
    for (int round = 0; round <= r; ++round) {
      unsigned long long m = c[0];
#pragma unroll
      for (int i = 1; i < SLOTS; ++i) m = (c[i] < m) ? c[i] : m;
      w = wave_min_u64(m);
#pragma unroll
      for (int i = 0; i < SLOTS; ++i)
        if (c[i] == w) c[i] = ~0ULL;
    }
    if (tid == 0) s_src = (int)(w & 0xffffffffu);
  }
  __syncthreads();
  const int src = __builtin_amdgcn_readfirstlane(s_src);

  const f4v* __restrict__ s = (const f4v*)(obs + (size_t)src * OBSROW);
  f4v* __restrict__ d       = (f4v*)(out + (size_t)b * OBSROW);
#pragma unroll 4
  for (int i = tid; i < OBSROW / 4; i += 256) {
    f4v v = s[i];  // cached load: L3 catches duplicate rows
    __builtin_nontemporal_store(v, &d[i]);
  }
}

extern "C" void kernel_launch(void* const* d_in, const int* in_sizes, int n_in,
                              void* d_out, int out_size, void* d_ws,
                              size_t ws_size, hipStream_t stream) {
  const float* q   = (const float*)d_in[0];  // [256,128]
  const float* k   = (const float*)d_in[1];  // [10000,128]
  const float* obs = (const float*)d_in[2];  // [10000,4,84,84]
  float* out = (float*)d_out;                // [10,256,4,84,84]

  // ws: part buffer = 256 * 209 * 10 * 8 = 4,279,040 B.
  unsigned long long* part = (unsigned long long*)d_ws;

  knn_part_fused<<<dim3(QCNT / QTILE, NCHUNK_M), 256, 0, stream>>>(q, k, part);
  knn_merge_gather_kernel<NCHUNK_M>
      <<<KSEL * QCNT, 256, 0, stream>>>(obs, part, out);
}